// Round 1
// baseline (309.037 us; speedup 1.0000x reference)
//
#include <hip/hip_runtime.h>
#include <stdint.h>

typedef unsigned short u16;
typedef short bf16x8 __attribute__((ext_vector_type(8)));
typedef short bf16x4 __attribute__((ext_vector_type(4)));
typedef float f32x4 __attribute__((ext_vector_type(4)));

#define NTOT   65536
#define NB     64
#define NEDGE  262144
#define H3     4096
#define LATD   512
#define NCLS_  160
#define K1     16384
#define K2     16544   // NCLS + 1024*16

static __device__ __forceinline__ u16 f2b(float f) {   // fp32 -> bf16 RNE
  uint32_t x = __float_as_uint(f);
  return (u16)((x + 0x7FFFu + ((x >> 16) & 1u)) >> 16);
}

// ---------- CSR build: histogram (+ fused Wc = Wg1@Wg2 in block 0) ----------
__global__ void k_hist(const int* __restrict__ E, int* __restrict__ cnt,
                       const float* __restrict__ Wg1, const float* __restrict__ Wg2,
                       float* __restrict__ Wc) {
  int e = blockIdx.x * 256 + threadIdx.x;
  atomicAdd(&cnt[E[NEDGE + e]], 1);
  if (blockIdx.x == 0 && threadIdx.x < 128) {
    int c = threadIdx.x >> 4, h = threadIdx.x & 15;
    float acc = 0.f;
    for (int k = 0; k < 512; ++k) acc += Wg1[c * 512 + k] * Wg2[k * 16 + h];
    Wc[c * 16 + h] = acc;
  }
}

// ---------- exclusive scan of 65536 counts (single block, 1024 threads) ----------
__global__ __launch_bounds__(1024) void k_scan(const int* __restrict__ cnt,
                                               int* __restrict__ off,
                                               int* __restrict__ cur) {
  __shared__ int wsum[16];
  const int t = threadIdx.x;
  const int lane = t & 63, w = t >> 6;
  const int base = t << 6;                          // 64 bins per thread
  int s = 0;
  const int4* c4 = (const int4*)(cnt + base);
  #pragma unroll 4
  for (int i = 0; i < 16; ++i) { int4 v = c4[i]; s += v.x + v.y + v.z + v.w; }
  int sc = s;
  #pragma unroll
  for (int d = 1; d < 64; d <<= 1) {
    int u = __shfl_up(sc, d);
    if (lane >= d) sc += u;
  }
  if (lane == 63) wsum[w] = sc;
  __syncthreads();
  if (w == 0 && lane < 16) {
    int v = wsum[lane];
    #pragma unroll
    for (int d = 1; d < 16; d <<= 1) {
      int u = __shfl_up(v, d);
      if (lane >= d) v += u;
    }
    wsum[lane] = v;
  }
  __syncthreads();
  int run = (w == 0 ? 0 : wsum[w - 1]) + (sc - s);
  int4* o4 = (int4*)(off + base);
  int4* u4 = (int4*)(cur + base);
  #pragma unroll 4
  for (int i = 0; i < 16; ++i) {
    int4 v = c4[i];
    int4 r;
    r.x = run; run += v.x;
    r.y = run; run += v.y;
    r.z = run; run += v.z;
    r.w = run; run += v.w;
    o4[i] = r; u4[i] = r;
  }
}

// ---------- scatter edges into CSR ----------
__global__ void k_scatter(const int* __restrict__ E, int* __restrict__ cur,
                          int* __restrict__ csr) {
  int e = blockIdx.x * 256 + threadIdx.x;
  int p = atomicAdd(&cur[E[NEDGE + e]], 1);
  csr[p] = E[e];
}

// ---------- atomic-free segment sum: Out[n][c] = sum_j In[csr[j]][c] ----------
__global__ void k_gather(const int* __restrict__ off, const int* __restrict__ cnt,
                         const int* __restrict__ csr, const float* __restrict__ In,
                         float* __restrict__ Out) {
  int t = blockIdx.x * 256 + threadIdx.x;           // NTOT*8 threads
  int n = t >> 3, c = t & 7;
  int b = off[n], e = b + cnt[n];
  float acc = 0.f;
  for (int j = b; j < e; ++j) acc += In[(size_t)csr[j] * 8 + c];
  Out[(size_t)n * 8 + c] = acc;
}

// ---------- per-node: gcn out (Abuf col 160+), mix (Mbuf), cls copy ----------
__global__ void k_nodes(const float* __restrict__ S2, const float* __restrict__ Wc,
                        const float* __restrict__ X,
                        const float* __restrict__ Wbox, const float* __restrict__ bbox,
                        const float* __restrict__ Wlbl, const float* __restrict__ blbl,
                        const float* __restrict__ cls,
                        u16* __restrict__ Abuf, u16* __restrict__ Mbuf) {
  int idx = blockIdx.x * 256 + threadIdx.x;
  if (idx < NB * NCLS_) {
    int m = idx / NCLS_, i = idx - m * NCLS_;
    Abuf[(size_t)m * K2 + i] = f2b(cls[idx]);
  }
  if (idx >= NTOT * 16) return;
  int n = idx >> 4, h = idx & 15;
  int m = n >> 10, nl = n & 1023;
  const float* s2 = S2 + (size_t)n * 8;
  float xg = 0.f;
  #pragma unroll
  for (int c = 0; c < 8; ++c) xg += s2[c] * Wc[c * 16 + h];
  Abuf[(size_t)m * K2 + 160 + nl * 16 + h] = f2b(xg);
  const float* xr = X + (size_t)n * 8;
  float box = bbox[h];
  #pragma unroll
  for (int c = 0; c < 7; ++c) box += xr[1 + c] * Wbox[c * 16 + h];
  box = box > 0.f ? box : 0.f;
  float lb = xr[0] * Wlbl[h] + blbl[h];
  lb = lb > 0.f ? lb : 0.f;
  Mbuf[(size_t)m * K1 + nl * 16 + h] = f2b(box + lb);
}

// ---------- skinny GEMM: slab[y] = A(bf16)[64,K] @ W(fp32->bf16)[K,Nw] ----------
// z selects param set (merged independent GEMMs). W staged via registers:
// fp32 load -> bf16 -> LDS [n][k] tile, XOR-swizzled, read as ds_read_b128.
//
// Software-pipelined (T3/T4): LDS double-buffered, raw s_barrier with COUNTED
// vmcnt so the 4 W-prefetch loads stay in flight across the barrier (one full
// iteration of latency cover), and the A global_load_lds is retired with
// vmcnt(4) — never vmcnt(0) — inside the loop.
__device__ __forceinline__ void gl16(const void* g, void* l) {
  __builtin_amdgcn_global_load_lds(
      (const __attribute__((address_space(1))) unsigned int*)g,
      (__attribute__((address_space(3))) unsigned int*)l, 16, 0, 0);
}

// One pipeline step. Reads step ST from (ArD,WrD); stages step ST+1 into
// (AwR,WwR) [A via gl16, W from regs wr0..3 loaded one iteration ago];
// issues W loads for ST+2 into wr0..3.
// VMEM order (pinned by sched_barrier): [gl16][4x W float2 loads].
// End-of-step: lgkmcnt(0) makes ds_writes visible, vmcnt(4) retires ONLY the
// gl16 (leaves 4 W loads in flight), raw s_barrier.
#define GEMM_STEP(ST, ArD, WrD, AwR, WwR)                                      \
  {                                                                            \
    const int i1 = (ST) + 1 < ns ? (ST) + 1 : ns - 1;                          \
    const int i2 = (ST) + 2 < ns ? (ST) + 2 : ns - 1;                          \
    gl16(gA + (size_t)i1 * 32, &AwR[t * 8]);                                   \
    __builtin_amdgcn_sched_barrier(0);                                         \
    bf16x8 a  = *(const bf16x8*)(&ArD[aoff]);                                  \
    bf16x8 b0 = *(const bf16x8*)(&WrD[fo]);                                    \
    bf16x8 b1 = *(const bf16x8*)(&WrD[fo + 512]);                              \
    bf16x8 b2 = *(const bf16x8*)(&WrD[fo + 1024]);                             \
    bf16x8 b3 = *(const bf16x8*)(&WrD[fo + 1536]);                             \
    bf16x4 p0 = { (short)f2b(wr0.x), (short)f2b(wr1.x),                        \
                  (short)f2b(wr2.x), (short)f2b(wr3.x) };                      \
    bf16x4 p1 = { (short)f2b(wr0.y), (short)f2b(wr1.y),                        \
                  (short)f2b(wr2.y), (short)f2b(wr3.y) };                      \
    *(bf16x4*)(&WwR[wtOff0]) = p0;                                             \
    *(bf16x4*)(&WwR[wtOff1]) = p1;                                             \
    const float* gWn = gW + (size_t)i2 * stepW;                                \
    wr0 = *(const float2*)(gWn);                                               \
    wr1 = *(const float2*)(gWn + Nw);                                          \
    wr2 = *(const float2*)(gWn + 2 * Nw);                                      \
    wr3 = *(const float2*)(gWn + 3 * Nw);                                      \
    ac0 = __builtin_amdgcn_mfma_f32_16x16x32_bf16(a, b0, ac0, 0, 0, 0);        \
    ac1 = __builtin_amdgcn_mfma_f32_16x16x32_bf16(a, b1, ac1, 0, 0, 0);        \
    ac2 = __builtin_amdgcn_mfma_f32_16x16x32_bf16(a, b2, ac2, 0, 0, 0);        \
    ac3 = __builtin_amdgcn_mfma_f32_16x16x32_bf16(a, b3, ac3, 0, 0, 0);        \
    asm volatile("s_waitcnt lgkmcnt(0)" ::: "memory");                         \
    asm volatile("s_waitcnt vmcnt(4)" ::: "memory");                           \
    __builtin_amdgcn_s_barrier();                                              \
    asm volatile("" ::: "memory");                                             \
  }

__global__ __launch_bounds__(256) void k_gemm(
    const u16* __restrict__ A0, const u16* __restrict__ A1, int lda0, int lda1,
    const float* __restrict__ W0, const float* __restrict__ W1, int Nw,
    int tot0, int tot1, int per0, int per1, int slabBase1,
    float* __restrict__ Cs)
{
  // 4 distinct objects (not one 2D array) so alias analysis can prove the
  // read buffer and the gl16/ds_write target buffer are disjoint (no
  // conservative vmcnt waits in front of the fragment ds_reads).
  __shared__ u16 lA0[2048];     // 64 rows x 32 k bf16, 16B-chunk XOR swizzle
  __shared__ u16 lA1[2048];
  __shared__ u16 lW0[2048];     // [n=64][k=32] bf16, k XOR-swizzled by 8*((n>>1)&3)
  __shared__ u16 lW1[2048];

  const u16* A; int lda; const float* W; int tot, per, slab;
  if (blockIdx.z == 0) { A = A0; lda = lda0; W = W0; tot = tot0; per = per0; slab = blockIdx.y; }
  else                 { A = A1; lda = lda1; W = W1; tot = tot1; per = per1; slab = slabBase1 + blockIdx.y; }

  const int n0  = blockIdx.x << 6;
  const int sp0 = blockIdx.y * per;
  int ns = tot - sp0; if (ns > per) ns = per;
  if (ns <= 0) return;
  const int t  = threadIdx.x;
  const int l  = t & 63;
  const int wv = t >> 6;

  // A staging (global_load_lds, 16B/thread)
  const int rA  = t >> 2;
  const int cAg = (t & 3) ^ ((rA >> 1) & 3);
  const u16* gA = A + (size_t)rA * lda + cAg * 8 + (size_t)sp0 * 32;

  // W register staging: thread t -> k rows 4q..4q+3 (q=t>>5), cols nc,nc+1
  const int q  = t >> 5;
  const int nc = (t & 31) * 2;
  const int mW = (t & 31) & 3;                       // swizzle sel = (nc>>1)&3
  const float* gW = W + (size_t)(sp0 * 32 + 4 * q) * Nw + n0 + nc;
  const int wtOff0 = nc * 32 + ((4 * q) ^ (8 * mW));
  const int wtOff1 = wtOff0 + 32;
  const size_t stepW = (size_t)32 * Nw;

  // A fragment read
  const int rAf  = (wv << 4) + (l & 15);
  const int aoff = rAf * 32 + (((l >> 4) ^ ((rAf >> 1) & 3)) << 3);
  // B fragment read: acc q' -> elem li*32 + 8*(g4^mR) + 512*q'
  const int g4 = l >> 4;
  const int li = l & 15;
  const int mR = (li >> 1) & 3;
  const int fo = li * 32 + 8 * (g4 ^ mR);

  f32x4 ac0 = {0.f, 0.f, 0.f, 0.f}, ac1 = ac0, ac2 = ac0, ac3 = ac0;

  // ---- prologue: stage step 0 into buf0, leave W(1) loads in flight ----
  float2 wr0, wr1, wr2, wr3;
  gl16(gA, &lA0[t * 8]);
  __builtin_amdgcn_sched_barrier(0);
  wr0 = *(const float2*)(gW);
  wr1 = *(const float2*)(gW + Nw);
  wr2 = *(const float2*)(gW + 2 * Nw);
  wr3 = *(const float2*)(gW + 3 * Nw);
  {
    bf16x4 p0 = { (short)f2b(wr0.x), (short)f2b(wr1.x),
                  (short)f2b(wr2.x), (short)f2b(wr3.x) };
    bf16x4 p1 = { (short)f2b(wr0.y), (short)f2b(wr1.y),
                  (short)f2b(wr2.y), (short)f2b(wr3.y) };
    *(bf16x4*)(&lW0[wtOff0]) = p0;
    *(bf16x4*)(&lW0[wtOff1]) = p1;
    const int i1p = 1 < ns ? 1 : 0;
    const float* gWn = gW + (size_t)i1p * stepW;
    wr0 = *(const float2*)(gWn);
    wr1 = *(const float2*)(gWn + Nw);
    wr2 = *(const float2*)(gWn + 2 * Nw);
    wr3 = *(const float2*)(gWn + 3 * Nw);
  }
  asm volatile("s_waitcnt lgkmcnt(0)" ::: "memory");
  asm volatile("s_waitcnt vmcnt(4)" ::: "memory");
  __builtin_amdgcn_s_barrier();
  asm volatile("" ::: "memory");

  // ---- main loop: 2-unrolled for static buffer names (precise aliasing) ----
  int st = 0;
  for (; st + 2 <= ns; st += 2) {
    GEMM_STEP(st,     lA0, lW0, lA1, lW1);
    GEMM_STEP(st + 1, lA1, lW1, lA0, lW0);
  }
  if (st < ns) {
    GEMM_STEP(st, lA0, lW0, lA1, lW1);
  }

  // slab store: col=l&15 (+16/acc), row=16*wv+4*(l>>4)+j
  const int col  = n0 + li;
  const int row0 = (wv << 4) + (g4 << 2);
  float* base = Cs + (size_t)slab * NB * Nw;
  #pragma unroll
  for (int j = 0; j < 4; ++j) {
    float* cp = base + (size_t)(row0 + j) * Nw + col;
    cp[0]  = ac0[j];
    cp[16] = ac1[j];
    cp[32] = ac2[j];
    cp[48] = ac3[j];
  }
}

// ---------- epilogues ----------
__global__ void k_ep12(const float* __restrict__ Cs,
                       const float* __restrict__ b1, const float* __restrict__ b2,
                       u16* __restrict__ A3) {
  int i = blockIdx.x * 256 + threadIdx.x;
  if (i >= NB * H3) return;
  float mix = b1[i & (H3 - 1)];
  float v   = b2[i & (H3 - 1)];
  #pragma unroll 4
  for (int s = 0; s < 16; ++s)  mix += Cs[(size_t)s * (NB * H3) + i];
  #pragma unroll 4
  for (int s = 16; s < 32; ++s) v   += Cs[(size_t)s * (NB * H3) + i];
  mix = mix > 0.f ? mix : 0.f;
  v   = v   > 0.f ? v   : 0.f;
  A3[i] = f2b(v + mix);
}

__global__ void k_ep(const float* __restrict__ Cs, int nslab, int slabElems,
                     const float* __restrict__ bias, u16* __restrict__ outb,
                     int colmask, int total) {
  int i = blockIdx.x * 256 + threadIdx.x;
  if (i >= total) return;
  float v = bias[i & colmask];
  #pragma unroll 4
  for (int s = 0; s < nslab; ++s) v += Cs[(size_t)s * slabElems + i];
  v = v > 0.f ? v : 0.f;
  outb[i] = f2b(v);
}

__global__ void k_ep5(const float* __restrict__ Cs, int nslab,
                      const float* __restrict__ bz, float* __restrict__ out) {
  int i = blockIdx.x * 256 + threadIdx.x;
  if (i >= NB * LATD) return;
  float v = bz[i & 511];
  #pragma unroll 4
  for (int s = 0; s < nslab; ++s) v += Cs[(size_t)s * (NB * LATD) + i];
  v = v > 0.f ? v : 0.f;
  out[i] = v;
  out[NB * LATD + i] = v;   // z_mean and z_logvar identical
}

extern "C" void kernel_launch(void* const* d_in, const int* in_sizes, int n_in,
                              void* d_out, int out_size, void* d_ws, size_t ws_size,
                              hipStream_t stream) {
  const int*   E    = (const int*)d_in[0];
  const float* X    = (const float*)d_in[1];
  const float* cls  = (const float*)d_in[2];
  const float* Wg1  = (const float*)d_in[3];
  const float* Wg2  = (const float*)d_in[4];
  const float* Wbox = (const float*)d_in[5];
  const float* bbox = (const float*)d_in[6];
  const float* Wlbl = (const float*)d_in[7];
  const float* blbl = (const float*)d_in[8];
  const float* Wd1  = (const float*)d_in[9];
  const float* bd1  = (const float*)d_in[10];
  const float* Wd2  = (const float*)d_in[11];
  const float* bd2  = (const float*)d_in[12];
  const float* Wd3  = (const float*)d_in[13];
  const float* bd3  = (const float*)d_in[14];
  const float* Wz   = (const float*)d_in[15];
  const float* bz   = (const float*)d_in[16];

  // workspace map (~45 MiB; ws ~1 GiB)
  char* ws = (char*)d_ws;
  int*   cnt  = (int*)  (ws + 0x000000);  // 256 KB (memset)
  int*   off  = (int*)  (ws + 0x040000);  // 256 KB
  int*   cur  = (int*)  (ws + 0x080000);  // 256 KB
  int*   csr  = (int*)  (ws + 0x0C0000);  // 1 MB
  float* S1   = (float*)(ws + 0x1C0000);  // 2 MB (fully overwritten)
  float* S2   = (float*)(ws + 0x3C0000);  // 2 MB (fully overwritten)
  float* Wc   = (float*)(ws + 0x5C0000);  // 512 B
  u16*   A3   = (u16*)  (ws + 0x5C1000);  // 512 KB
  u16*   A4   = (u16*)  (ws + 0x641000);  // 512 KB
  u16*   A5   = (u16*)  (ws + 0x6C1000);  // 512 KB
  u16*   Mbuf = (u16*)  (ws + 0x741000);  // 2 MB
  u16*   Abuf = (u16*)  (ws + 0x941000);  // ~2.02 MB
  float* Cslb = (float*)(ws + 0xB50000);  // 32 slabs x 1 MB

  hipMemsetAsync(cnt, 0, 0x40000, stream);
  k_hist   <<<NEDGE / 256, 256, 0, stream>>>(E, cnt, Wg1, Wg2, Wc);
  k_scan   <<<1, 1024, 0, stream>>>(cnt, off, cur);
  k_scatter<<<NEDGE / 256, 256, 0, stream>>>(E, cur, csr);
  k_gather <<<NTOT * 8 / 256, 256, 0, stream>>>(off, cnt, csr, X,  S1);
  k_gather <<<NTOT * 8 / 256, 256, 0, stream>>>(off, cnt, csr, S1, S2);
  k_nodes  <<<NTOT * 16 / 256, 256, 0, stream>>>(S2, Wc, X, Wbox, bbox, Wlbl, blbl,
                                                 cls, Abuf, Mbuf);

  // GEMM1+2 merged (z=0: Mbuf@Wd1 -> slabs 0..15; z=1: Abuf@Wd2 -> slabs 16..31)
  { dim3 g(64, 16, 2);
    k_gemm<<<g, 256, 0, stream>>>(Mbuf, Abuf, K1, K2, Wd1, Wd2, H3,
                                  512, 517, 32, 33, 16, Cslb); }
  k_ep12<<<NB * H3 / 256, 256, 0, stream>>>(Cslb, bd1, bd2, A3);

  // GEMM3: A4 = relu(A3 @ Wd3 + b3)
  { dim3 g(64, 16, 1);
    k_gemm<<<g, 256, 0, stream>>>(A3, A3, H3, H3, Wd3, Wd3, H3,
                                  128, 128, 8, 8, 0, Cslb); }
  k_ep<<<NB * H3 / 256, 256, 0, stream>>>(Cslb, 16, NB * H3, bd3, A4, H3 - 1, NB * H3);

  // GEMM4: A5 = relu(A4 @ Wd3 + b3)
  { dim3 g(64, 16, 1);
    k_gemm<<<g, 256, 0, stream>>>(A4, A4, H3, H3, Wd3, Wd3, H3,
                                  128, 128, 8, 8, 0, Cslb); }
  k_ep<<<NB * H3 / 256, 256, 0, stream>>>(Cslb, 16, NB * H3, bd3, A5, H3 - 1, NB * H3);

  // GEMM5: z = relu(A5 @ Wz + bz), written to both output halves
  { dim3 g(8, 32, 1);
    k_gemm<<<g, 256, 0, stream>>>(A5, A5, H3, H3, Wz, Wz, LATD,
                                  128, 128, 4, 4, 0, Cslb); }
  k_ep5<<<NB * LATD / 256, 256, 0, stream>>>(Cslb, 32, bz, (float*)d_out);
}

// Round 2
// 306.650 us; speedup vs baseline: 1.0078x; 1.0078x over previous
//
#include <hip/hip_runtime.h>
#include <stdint.h>

typedef unsigned short u16;
typedef short bf16x8 __attribute__((ext_vector_type(8)));
typedef short bf16x4 __attribute__((ext_vector_type(4)));
typedef float f32x4 __attribute__((ext_vector_type(4)));

#define NTOT   65536
#define NB     64
#define NEDGE  262144
#define H3     4096
#define LATD   512
#define NCLS_  160
#define K1     16384
#define K2     16544   // NCLS + 1024*16

static __device__ __forceinline__ u16 f2b(float f) {   // fp32 -> bf16 RNE
  uint32_t x = __float_as_uint(f);
  return (u16)((x + 0x7FFFu + ((x >> 16) & 1u)) >> 16);
}

// ---------- CSR build: histogram (+ fused Wc = Wg1@Wg2 in block 0) ----------
__global__ void k_hist(const int* __restrict__ E, int* __restrict__ cnt,
                       const float* __restrict__ Wg1, const float* __restrict__ Wg2,
                       float* __restrict__ Wc) {
  int e = blockIdx.x * 256 + threadIdx.x;
  atomicAdd(&cnt[E[NEDGE + e]], 1);
  if (blockIdx.x == 0 && threadIdx.x < 128) {
    int c = threadIdx.x >> 4, h = threadIdx.x & 15;
    float acc = 0.f;
    for (int k = 0; k < 512; ++k) acc += Wg1[c * 512 + k] * Wg2[k * 16 + h];
    Wc[c * 16 + h] = acc;
  }
}

// ---------- exclusive scan of 65536 counts (single block, 1024 threads) ----------
__global__ __launch_bounds__(1024) void k_scan(const int* __restrict__ cnt,
                                               int* __restrict__ off,
                                               int* __restrict__ cur) {
  __shared__ int wsum[16];
  const int t = threadIdx.x;
  const int lane = t & 63, w = t >> 6;
  const int base = t << 6;                          // 64 bins per thread
  int s = 0;
  const int4* c4 = (const int4*)(cnt + base);
  #pragma unroll 4
  for (int i = 0; i < 16; ++i) { int4 v = c4[i]; s += v.x + v.y + v.z + v.w; }
  int sc = s;
  #pragma unroll
  for (int d = 1; d < 64; d <<= 1) {
    int u = __shfl_up(sc, d);
    if (lane >= d) sc += u;
  }
  if (lane == 63) wsum[w] = sc;
  __syncthreads();
  if (w == 0 && lane < 16) {
    int v = wsum[lane];
    #pragma unroll
    for (int d = 1; d < 16; d <<= 1) {
      int u = __shfl_up(v, d);
      if (lane >= d) v += u;
    }
    wsum[lane] = v;
  }
  __syncthreads();
  int run = (w == 0 ? 0 : wsum[w - 1]) + (sc - s);
  int4* o4 = (int4*)(off + base);
  int4* u4 = (int4*)(cur + base);
  #pragma unroll 4
  for (int i = 0; i < 16; ++i) {
    int4 v = c4[i];
    int4 r;
    r.x = run; run += v.x;
    r.y = run; run += v.y;
    r.z = run; run += v.z;
    r.w = run; run += v.w;
    o4[i] = r; u4[i] = r;
  }
}

// ---------- scatter edges into CSR ----------
__global__ void k_scatter(const int* __restrict__ E, int* __restrict__ cur,
                          int* __restrict__ csr) {
  int e = blockIdx.x * 256 + threadIdx.x;
  int p = atomicAdd(&cur[E[NEDGE + e]], 1);
  csr[p] = E[e];
}

// ---------- atomic-free segment sum: Out[n][c] = sum_j In[csr[j]][c] ----------
__global__ void k_gather(const int* __restrict__ off, const int* __restrict__ cnt,
                         const int* __restrict__ csr, const float* __restrict__ In,
                         float* __restrict__ Out) {
  int t = blockIdx.x * 256 + threadIdx.x;           // NTOT*8 threads
  int n = t >> 3, c = t & 7;
  int b = off[n], e = b + cnt[n];
  float acc = 0.f;
  for (int j = b; j < e; ++j) acc += In[(size_t)csr[j] * 8 + c];
  Out[(size_t)n * 8 + c] = acc;
}

// ---------- per-node: gcn out (Abuf col 160+), mix (Mbuf), cls copy ----------
__global__ void k_nodes(const float* __restrict__ S2, const float* __restrict__ Wc,
                        const float* __restrict__ X,
                        const float* __restrict__ Wbox, const float* __restrict__ bbox,
                        const float* __restrict__ Wlbl, const float* __restrict__ blbl,
                        const float* __restrict__ cls,
                        u16* __restrict__ Abuf, u16* __restrict__ Mbuf) {
  int idx = blockIdx.x * 256 + threadIdx.x;
  if (idx < NB * NCLS_) {
    int m = idx / NCLS_, i = idx - m * NCLS_;
    Abuf[(size_t)m * K2 + i] = f2b(cls[idx]);
  }
  if (idx >= NTOT * 16) return;
  int n = idx >> 4, h = idx & 15;
  int m = n >> 10, nl = n & 1023;
  const float* s2 = S2 + (size_t)n * 8;
  float xg = 0.f;
  #pragma unroll
  for (int c = 0; c < 8; ++c) xg += s2[c] * Wc[c * 16 + h];
  Abuf[(size_t)m * K2 + 160 + nl * 16 + h] = f2b(xg);
  const float* xr = X + (size_t)n * 8;
  float box = bbox[h];
  #pragma unroll
  for (int c = 0; c < 7; ++c) box += xr[1 + c] * Wbox[c * 16 + h];
  box = box > 0.f ? box : 0.f;
  float lb = xr[0] * Wlbl[h] + blbl[h];
  lb = lb > 0.f ? lb : 0.f;
  Mbuf[(size_t)m * K1 + nl * 16 + h] = f2b(box + lb);
}

// ---------- skinny GEMM: slab[y] = A(bf16)[64,K] @ W(fp32->bf16)[K,Nw] ----------
// All-register staging, 2-deep software pipeline, NO global_load_lds (the DMA
// poisons the in-order vmcnt queue: retiring it forcibly drains every older
// prefetch load -> zero latency cover, measured neutral in r0/r1).
// Per step each thread: 5 plain loads (tile st+3) issued, reg set from st-2
// written to LDS, fragments read, 4 MFMA, lgkmcnt(0)+s_barrier. The only vmem
// wait is the compiler's counted vmcnt(5) at the write phase — 2 steps of
// latency cover. No vmcnt at the barrier.
#define CVTPK(dst, lo, hi) \
  asm("v_cvt_pk_bf16_f32 %0, %1, %2" : "=v"(dst) : "v"(lo), "v"(hi))

// Reads step ST from (ArD,WrD); writes tile ST+1 (held in reg set aS/w0S..w3S,
// issued at step ST-2) into (AwR,WwR); re-issues that set with tile ST+3.
#define GEMM_STEP(ST, ArD, WrD, AwR, WwR, aS, w0S, w1S, w2S, w3S)              \
  {                                                                            \
    bf16x8 a  = *(const bf16x8*)(&ArD[aoff]);                                  \
    bf16x8 b0 = *(const bf16x8*)(&WrD[fo]);                                    \
    bf16x8 b1 = *(const bf16x8*)(&WrD[fo + 512]);                              \
    bf16x8 b2 = *(const bf16x8*)(&WrD[fo + 1024]);                             \
    bf16x8 b3 = *(const bf16x8*)(&WrD[fo + 1536]);                             \
    /* write phase: stage tile ST+1 from regs (2-step-old loads) */            \
    *(int4*)(&AwR[t * 8]) = aS;                                                \
    uint32_t r0, r1, r2, r3;                                                   \
    CVTPK(r0, w0S.x, w1S.x);                                                   \
    CVTPK(r1, w2S.x, w3S.x);                                                   \
    CVTPK(r2, w0S.y, w1S.y);                                                   \
    CVTPK(r3, w2S.y, w3S.y);                                                   \
    { uint2 p0 = {r0, r1}; uint2 p1 = {r2, r3};                                \
      *(uint2*)(&WwR[wtOff0]) = p0;                                            \
      *(uint2*)(&WwR[wtOff1]) = p1; }                                          \
    /* issue phase: tile ST+3 into the set just consumed */                    \
    { const int ii = (ST) + 3 < ns ? (ST) + 3 : ns - 1;                        \
      const u16*  ga = gA + (size_t)ii * 32;                                   \
      const float* gw = gW + (size_t)ii * stepW;                               \
      aS  = *(const int4*)ga;                                                  \
      w0S = *(const float2*)(gw);                                              \
      w1S = *(const float2*)(gw + Nw);                                         \
      w2S = *(const float2*)(gw + 2 * Nw);                                     \
      w3S = *(const float2*)(gw + 3 * Nw); }                                   \
    ac0 = __builtin_amdgcn_mfma_f32_16x16x32_bf16(a, b0, ac0, 0, 0, 0);        \
    ac1 = __builtin_amdgcn_mfma_f32_16x16x32_bf16(a, b1, ac1, 0, 0, 0);        \
    ac2 = __builtin_amdgcn_mfma_f32_16x16x32_bf16(a, b2, ac2, 0, 0, 0);        \
    ac3 = __builtin_amdgcn_mfma_f32_16x16x32_bf16(a, b3, ac3, 0, 0, 0);        \
    asm volatile("s_waitcnt lgkmcnt(0)" ::: "memory");                         \
    __builtin_amdgcn_s_barrier();                                              \
    asm volatile("" ::: "memory");                                             \
  }

__global__ __launch_bounds__(256) void k_gemm(
    const u16* __restrict__ A0, const u16* __restrict__ A1, int lda0, int lda1,
    const float* __restrict__ W0, const float* __restrict__ W1, int Nw,
    int tot0, int tot1, int per0, int per1, int slabBase1,
    float* __restrict__ Cs)
{
  __shared__ u16 lA0[2048];     // 64 rows x 32 k bf16, 16B-chunk XOR swizzle
  __shared__ u16 lA1[2048];
  __shared__ u16 lW0[2048];     // [n=64][k=32] bf16, k XOR-swizzled by 8*((n>>1)&3)
  __shared__ u16 lW1[2048];

  const u16* A; int lda; const float* W; int tot, per, slab;
  if (blockIdx.z == 0) { A = A0; lda = lda0; W = W0; tot = tot0; per = per0; slab = blockIdx.y; }
  else                 { A = A1; lda = lda1; W = W1; tot = tot1; per = per1; slab = slabBase1 + blockIdx.y; }

  const int n0  = blockIdx.x << 6;
  const int sp0 = blockIdx.y * per;
  int ns = tot - sp0; if (ns > per) ns = per;
  if (ns <= 0) return;
  const int t  = threadIdx.x;
  const int l  = t & 63;
  const int wv = t >> 6;

  // A staging: thread t -> row rA, 16B chunk cAg (global addr pre-swizzled,
  // LDS write linear at t*8 -> same layout the fragment reader expects)
  const int rA  = t >> 2;
  const int cAg = (t & 3) ^ ((rA >> 1) & 3);
  const u16* gA = A + (size_t)rA * lda + cAg * 8 + (size_t)sp0 * 32;

  // W register staging: thread t -> k rows 4q..4q+3 (q=t>>5), cols nc,nc+1
  const int q  = t >> 5;
  const int nc = (t & 31) * 2;
  const int mW = (t & 31) & 3;                       // swizzle sel = (nc>>1)&3
  const float* gW = W + (size_t)(sp0 * 32 + 4 * q) * Nw + n0 + nc;
  const int wtOff0 = nc * 32 + ((4 * q) ^ (8 * mW));
  const int wtOff1 = wtOff0 + 32;
  const size_t stepW = (size_t)32 * Nw;

  // A fragment read
  const int rAf  = (wv << 4) + (l & 15);
  const int aoff = rAf * 32 + (((l >> 4) ^ ((rAf >> 1) & 3)) << 3);
  // B fragment read: acc q' -> elem li*32 + 8*(g4^mR) + 512*q'
  const int g4 = l >> 4;
  const int li = l & 15;
  const int mR = (li >> 1) & 3;
  const int fo = li * 32 + 8 * (g4 ^ mR);

  f32x4 ac0 = {0.f, 0.f, 0.f, 0.f}, ac1 = ac0, ac2 = ac0, ac3 = ac0;

  // reg sets (static names only — rule #20)
  int4 aS0, aS1;
  float2 w00, w01, w02, w03;      // set0
  float2 w10, w11, w12, w13;      // set1

  // ---- prologue ----
  // queue: [tile0 x5 -> set0][tile1 x5 -> set1]; write tile0 (waits vmcnt(5));
  // re-issue set0 <- tile2; lgkm+barrier. Steady state: step st consumes set
  // (st+1)&1 holding tile st+1 (issued 2 steps earlier), re-issues tile st+3.
  const int i1 = 1 < ns ? 1 : ns - 1;
  const int i2 = 2 < ns ? 2 : ns - 1;
  aS0 = *(const int4*)(gA);
  w00 = *(const float2*)(gW);
  w01 = *(const float2*)(gW + Nw);
  w02 = *(const float2*)(gW + 2 * Nw);
  w03 = *(const float2*)(gW + 3 * Nw);
  {
    const u16*  ga = gA + (size_t)i1 * 32;
    const float* gw = gW + (size_t)i1 * stepW;
    aS1 = *(const int4*)ga;
    w10 = *(const float2*)(gw);
    w11 = *(const float2*)(gw + Nw);
    w12 = *(const float2*)(gw + 2 * Nw);
    w13 = *(const float2*)(gw + 3 * Nw);
  }
  *(int4*)(&lA0[t * 8]) = aS0;
  {
    uint32_t r0, r1, r2, r3;
    CVTPK(r0, w00.x, w01.x);
    CVTPK(r1, w02.x, w03.x);
    CVTPK(r2, w00.y, w01.y);
    CVTPK(r3, w02.y, w03.y);
    uint2 p0 = {r0, r1}; uint2 p1 = {r2, r3};
    *(uint2*)(&lW0[wtOff0]) = p0;
    *(uint2*)(&lW0[wtOff1]) = p1;
  }
  {
    const u16*  ga = gA + (size_t)i2 * 32;
    const float* gw = gW + (size_t)i2 * stepW;
    aS0 = *(const int4*)ga;
    w00 = *(const float2*)(gw);
    w01 = *(const float2*)(gw + Nw);
    w02 = *(const float2*)(gw + 2 * Nw);
    w03 = *(const float2*)(gw + 3 * Nw);
  }
  asm volatile("s_waitcnt lgkmcnt(0)" ::: "memory");
  __builtin_amdgcn_s_barrier();
  asm volatile("" ::: "memory");

  // ---- main loop: 2-unrolled for static buffer/set names ----
  int st = 0;
  for (; st + 2 <= ns; st += 2) {
    GEMM_STEP(st,     lA0, lW0, lA1, lW1, aS1, w10, w11, w12, w13);
    GEMM_STEP(st + 1, lA1, lW1, lA0, lW0, aS0, w00, w01, w02, w03);
  }
  if (st < ns) {
    GEMM_STEP(st, lA0, lW0, lA1, lW1, aS1, w10, w11, w12, w13);
  }

  // slab store: col=l&15 (+16/acc), row=16*wv+4*(l>>4)+j
  const int col  = n0 + li;
  const int row0 = (wv << 4) + (g4 << 2);
  float* base = Cs + (size_t)slab * NB * Nw;
  #pragma unroll
  for (int j = 0; j < 4; ++j) {
    float* cp = base + (size_t)(row0 + j) * Nw + col;
    cp[0]  = ac0[j];
    cp[16] = ac1[j];
    cp[32] = ac2[j];
    cp[48] = ac3[j];
  }
}

// ---------- epilogues ----------
__global__ void k_ep12(const float* __restrict__ Cs,
                       const float* __restrict__ b1, const float* __restrict__ b2,
                       u16* __restrict__ A3) {
  int i = blockIdx.x * 256 + threadIdx.x;
  if (i >= NB * H3) return;
  float mix = b1[i & (H3 - 1)];
  float v   = b2[i & (H3 - 1)];
  #pragma unroll 4
  for (int s = 0; s < 16; ++s)  mix += Cs[(size_t)s * (NB * H3) + i];
  #pragma unroll 4
  for (int s = 16; s < 32; ++s) v   += Cs[(size_t)s * (NB * H3) + i];
  mix = mix > 0.f ? mix : 0.f;
  v   = v   > 0.f ? v   : 0.f;
  A3[i] = f2b(v + mix);
}

__global__ void k_ep(const float* __restrict__ Cs, int nslab, int slabElems,
                     const float* __restrict__ bias, u16* __restrict__ outb,
                     int colmask, int total) {
  int i = blockIdx.x * 256 + threadIdx.x;
  if (i >= total) return;
  float v = bias[i & colmask];
  #pragma unroll 4
  for (int s = 0; s < nslab; ++s) v += Cs[(size_t)s * slabElems + i];
  v = v > 0.f ? v : 0.f;
  outb[i] = f2b(v);
}

__global__ void k_ep5(const float* __restrict__ Cs, int nslab,
                      const float* __restrict__ bz, float* __restrict__ out) {
  int i = blockIdx.x * 256 + threadIdx.x;
  if (i >= NB * LATD) return;
  float v = bz[i & 511];
  #pragma unroll 4
  for (int s = 0; s < nslab; ++s) v += Cs[(size_t)s * (NB * LATD) + i];
  v = v > 0.f ? v : 0.f;
  out[i] = v;
  out[NB * LATD + i] = v;   // z_mean and z_logvar identical
}

extern "C" void kernel_launch(void* const* d_in, const int* in_sizes, int n_in,
                              void* d_out, int out_size, void* d_ws, size_t ws_size,
                              hipStream_t stream) {
  const int*   E    = (const int*)d_in[0];
  const float* X    = (const float*)d_in[1];
  const float* cls  = (const float*)d_in[2];
  const float* Wg1  = (const float*)d_in[3];
  const float* Wg2  = (const float*)d_in[4];
  const float* Wbox = (const float*)d_in[5];
  const float* bbox = (const float*)d_in[6];
  const float* Wlbl = (const float*)d_in[7];
  const float* blbl = (const float*)d_in[8];
  const float* Wd1  = (const float*)d_in[9];
  const float* bd1  = (const float*)d_in[10];
  const float* Wd2  = (const float*)d_in[11];
  const float* bd2  = (const float*)d_in[12];
  const float* Wd3  = (const float*)d_in[13];
  const float* bd3  = (const float*)d_in[14];
  const float* Wz   = (const float*)d_in[15];
  const float* bz   = (const float*)d_in[16];

  // workspace map (~45 MiB; ws ~1 GiB)
  char* ws = (char*)d_ws;
  int*   cnt  = (int*)  (ws + 0x000000);  // 256 KB (memset)
  int*   off  = (int*)  (ws + 0x040000);  // 256 KB
  int*   cur  = (int*)  (ws + 0x080000);  // 256 KB
  int*   csr  = (int*)  (ws + 0x0C0000);  // 1 MB
  float* S1   = (float*)(ws + 0x1C0000);  // 2 MB (fully overwritten)
  float* S2   = (float*)(ws + 0x3C0000);  // 2 MB (fully overwritten)
  float* Wc   = (float*)(ws + 0x5C0000);  // 512 B
  u16*   A3   = (u16*)  (ws + 0x5C1000);  // 512 KB
  u16*   A4   = (u16*)  (ws + 0x641000);  // 512 KB
  u16*   A5   = (u16*)  (ws + 0x6C1000);  // 512 KB
  u16*   Mbuf = (u16*)  (ws + 0x741000);  // 2 MB
  u16*   Abuf = (u16*)  (ws + 0x941000);  // ~2.02 MB
  float* Cslb = (float*)(ws + 0xB50000);  // 32 slabs x 1 MB

  hipMemsetAsync(cnt, 0, 0x40000, stream);
  k_hist   <<<NEDGE / 256, 256, 0, stream>>>(E, cnt, Wg1, Wg2, Wc);
  k_scan   <<<1, 1024, 0, stream>>>(cnt, off, cur);
  k_scatter<<<NEDGE / 256, 256, 0, stream>>>(E, cur, csr);
  k_gather <<<NTOT * 8 / 256, 256, 0, stream>>>(off, cnt, csr, X,  S1);
  k_gather <<<NTOT * 8 / 256, 256, 0, stream>>>(off, cnt, csr, S1, S2);
  k_nodes  <<<NTOT * 16 / 256, 256, 0, stream>>>(S2, Wc, X, Wbox, bbox, Wlbl, blbl,
                                                 cls, Abuf, Mbuf);

  // GEMM1+2 merged (z=0: Mbuf@Wd1 -> slabs 0..15; z=1: Abuf@Wd2 -> slabs 16..31)
  { dim3 g(64, 16, 2);
    k_gemm<<<g, 256, 0, stream>>>(Mbuf, Abuf, K1, K2, Wd1, Wd2, H3,
                                  512, 517, 32, 33, 16, Cslb); }
  k_ep12<<<NB * H3 / 256, 256, 0, stream>>>(Cslb, bd1, bd2, A3);

  // GEMM3: A4 = relu(A3 @ Wd3 + b3)
  { dim3 g(64, 16, 1);
    k_gemm<<<g, 256, 0, stream>>>(A3, A3, H3, H3, Wd3, Wd3, H3,
                                  128, 128, 8, 8, 0, Cslb); }
  k_ep<<<NB * H3 / 256, 256, 0, stream>>>(Cslb, 16, NB * H3, bd3, A4, H3 - 1, NB * H3);

  // GEMM4: A5 = relu(A4 @ Wd3 + b3)
  { dim3 g(64, 16, 1);
    k_gemm<<<g, 256, 0, stream>>>(A4, A4, H3, H3, Wd3, Wd3, H3,
                                  128, 128, 8, 8, 0, Cslb); }
  k_ep<<<NB * H3 / 256, 256, 0, stream>>>(Cslb, 16, NB * H3, bd3, A5, H3 - 1, NB * H3);

  // GEMM5: z = relu(A5 @ Wz + bz), written to both output halves
  { dim3 g(8, 32, 1);
    k_gemm<<<g, 256, 0, stream>>>(A5, A5, H3, H3, Wz, Wz, LATD,
                                  128, 128, 4, 4, 0, Cslb); }
  k_ep5<<<NB * LATD / 256, 256, 0, stream>>>(Cslb, 32, bz, (float*)d_out);
}

// Round 3
// 296.736 us; speedup vs baseline: 1.0415x; 1.0334x over previous
//
#include <hip/hip_runtime.h>
#include <stdint.h>

typedef unsigned short u16;
typedef short bf16x8 __attribute__((ext_vector_type(8)));
typedef short bf16x4 __attribute__((ext_vector_type(4)));
typedef float f32x4 __attribute__((ext_vector_type(4)));

#define NTOT   65536
#define NB     64
#define NEDGE  262144
#define H3     4096
#define LATD   512
#define NCLS_  160
#define K1     16384
#define K2     16544   // NCLS + 1024*16

static __device__ __forceinline__ u16 f2b(float f) {   // fp32 -> bf16 RNE
  uint32_t x = __float_as_uint(f);
  return (u16)((x + 0x7FFFu + ((x >> 16) & 1u)) >> 16);
}

// ---------- CSR build: histogram (+ fused Wc = Wg1@Wg2 in block 0) ----------
__global__ void k_hist(const int* __restrict__ E, int* __restrict__ cnt,
                       const float* __restrict__ Wg1, const float* __restrict__ Wg2,
                       float* __restrict__ Wc) {
  int e = blockIdx.x * 256 + threadIdx.x;
  atomicAdd(&cnt[E[NEDGE + e]], 1);
  if (blockIdx.x == 0 && threadIdx.x < 128) {
    int c = threadIdx.x >> 4, h = threadIdx.x & 15;
    float acc = 0.f;
    for (int k = 0; k < 512; ++k) acc += Wg1[c * 512 + k] * Wg2[k * 16 + h];
    Wc[c * 16 + h] = acc;
  }
}

// ---------- exclusive scan of 65536 counts (single block, 1024 threads) ----------
__global__ __launch_bounds__(1024) void k_scan(const int* __restrict__ cnt,
                                               int* __restrict__ off,
                                               int* __restrict__ cur) {
  __shared__ int wsum[16];
  const int t = threadIdx.x;
  const int lane = t & 63, w = t >> 6;
  const int base = t << 6;                          // 64 bins per thread
  int s = 0;
  const int4* c4 = (const int4*)(cnt + base);
  #pragma unroll 4
  for (int i = 0; i < 16; ++i) { int4 v = c4[i]; s += v.x + v.y + v.z + v.w; }
  int sc = s;
  #pragma unroll
  for (int d = 1; d < 64; d <<= 1) {
    int u = __shfl_up(sc, d);
    if (lane >= d) sc += u;
  }
  if (lane == 63) wsum[w] = sc;
  __syncthreads();
  if (w == 0 && lane < 16) {
    int v = wsum[lane];
    #pragma unroll
    for (int d = 1; d < 16; d <<= 1) {
      int u = __shfl_up(v, d);
      if (lane >= d) v += u;
    }
    wsum[lane] = v;
  }
  __syncthreads();
  int run = (w == 0 ? 0 : wsum[w - 1]) + (sc - s);
  int4* o4 = (int4*)(off + base);
  int4* u4 = (int4*)(cur + base);
  #pragma unroll 4
  for (int i = 0; i < 16; ++i) {
    int4 v = c4[i];
    int4 r;
    r.x = run; run += v.x;
    r.y = run; run += v.y;
    r.z = run; run += v.z;
    r.w = run; run += v.w;
    o4[i] = r; u4[i] = r;
  }
}

// ---------- scatter edges into CSR ----------
__global__ void k_scatter(const int* __restrict__ E, int* __restrict__ cur,
                          int* __restrict__ csr) {
  int e = blockIdx.x * 256 + threadIdx.x;
  int p = atomicAdd(&cur[E[NEDGE + e]], 1);
  csr[p] = E[e];
}

// ---------- atomic-free segment sum: Out[n][c] = sum_j In[csr[j]][c] ----------
__global__ void k_gather(const int* __restrict__ off, const int* __restrict__ cnt,
                         const int* __restrict__ csr, const float* __restrict__ In,
                         float* __restrict__ Out) {
  int t = blockIdx.x * 256 + threadIdx.x;           // NTOT*8 threads
  int n = t >> 3, c = t & 7;
  int b = off[n], e = b + cnt[n];
  float acc = 0.f;
  for (int j = b; j < e; ++j) acc += In[(size_t)csr[j] * 8 + c];
  Out[(size_t)n * 8 + c] = acc;
}

// ---------- per-node: gcn out (Abuf col 160+), mix (Mbuf), cls copy ----------
__global__ void k_nodes(const float* __restrict__ S2, const float* __restrict__ Wc,
                        const float* __restrict__ X,
                        const float* __restrict__ Wbox, const float* __restrict__ bbox,
                        const float* __restrict__ Wlbl, const float* __restrict__ blbl,
                        const float* __restrict__ cls,
                        u16* __restrict__ Abuf, u16* __restrict__ Mbuf) {
  int idx = blockIdx.x * 256 + threadIdx.x;
  if (idx < NB * NCLS_) {
    int m = idx / NCLS_, i = idx - m * NCLS_;
    Abuf[(size_t)m * K2 + i] = f2b(cls[idx]);
  }
  if (idx >= NTOT * 16) return;
  int n = idx >> 4, h = idx & 15;
  int m = n >> 10, nl = n & 1023;
  const float* s2 = S2 + (size_t)n * 8;
  float xg = 0.f;
  #pragma unroll
  for (int c = 0; c < 8; ++c) xg += s2[c] * Wc[c * 16 + h];
  Abuf[(size_t)m * K2 + 160 + nl * 16 + h] = f2b(xg);
  const float* xr = X + (size_t)n * 8;
  float box = bbox[h];
  #pragma unroll
  for (int c = 0; c < 7; ++c) box += xr[1 + c] * Wbox[c * 16 + h];
  box = box > 0.f ? box : 0.f;
  float lb = xr[0] * Wlbl[h] + blbl[h];
  lb = lb > 0.f ? lb : 0.f;
  Mbuf[(size_t)m * K1 + nl * 16 + h] = f2b(box + lb);
}

// ---------- skinny GEMM: slab[y] = A(bf16)[64,K] @ W(fp32->bf16)[K,BN] ----------
// BN=256 tile (was 64): per step each block reads W as 32 rows x 1KB CONTIGUOUS
// (each wave-instruction = 1KB lane-linear burst) instead of 32 x 256B strided
// chunks. Rounds 0-2 proved scheduling is not the limit (3 different pipelines
// all = 175us @ 1.84 TB/s = 29% HBM eff.); the strided 256B pattern across 2048
// blocks is. 4 waves, each: 4 rowtiles x 4 coltiles of 16x16x32 MFMA.
// W path: f32x4 regs -> v_cvt_pk_bf16_f32 -> LDS [n=256][k=32] bf16, k-chunk
// XOR-swizzled by sw(n)=((n>>1)^(n>>2))&3 (2-way on frag reads = free).
#define CVTPK(dst, lo, hi) \
  asm("v_cvt_pk_bf16_f32 %0, %1, %2" : "=v"(dst) : "v"(lo), "v"(hi))

// pack 4 n-columns (n = l*4+I2) of this thread's 8-row k-micro-tile into LDS
#define WPACK(I2, WwR)                                                         \
  { const int n_ = (l << 2) + (I2);                                            \
    const int sw_ = ((n_ >> 1) ^ (n_ >> 2)) & 3;                               \
    uint32_t q0, q1, q2, q3;                                                   \
    CVTPK(q0, ws0[I2], ws1[I2]);                                               \
    CVTPK(q1, ws2[I2], ws3[I2]);                                               \
    CVTPK(q2, ws4[I2], ws5[I2]);                                               \
    CVTPK(q3, ws6[I2], ws7[I2]);                                               \
    uint4 pk_ = {q0, q1, q2, q3};                                              \
    *(uint4*)(&WwR[n_ * 32 + ((wv ^ sw_) << 3)]) = pk_; }

// issue tile II's loads: 8x f32x4 W (1KB contiguous per wave-instr) + 1 A int4
#define WLOADS(II)                                                             \
  { const float* gw_ = gW + (size_t)(II) * stepW;                              \
    ws0 = *(const f32x4*)(gw_);                                                \
    ws1 = *(const f32x4*)(gw_ + Nw);                                           \
    ws2 = *(const f32x4*)(gw_ + 2 * Nw);                                       \
    ws3 = *(const f32x4*)(gw_ + 3 * Nw);                                       \
    ws4 = *(const f32x4*)(gw_ + 4 * Nw);                                       \
    ws5 = *(const f32x4*)(gw_ + 5 * Nw);                                       \
    ws6 = *(const f32x4*)(gw_ + 6 * Nw);                                       \
    ws7 = *(const f32x4*)(gw_ + 7 * Nw);                                       \
    aS  = *(const int4*)(gA + (size_t)(II) * 32); }

#define MFMA_BF16 __builtin_amdgcn_mfma_f32_16x16x32_bf16

// step ST: compute tile ST from (ArD,WrD); write regs (tile ST+1, loaded one
// step ago -> one full step of latency cover) into (AwR,WwR); issue ST+2.
#define GEMM_STEP(ST, ArD, WrD, AwR, WwR)                                      \
  {                                                                            \
    bf16x8 a0 = *(const bf16x8*)(&ArD[foA]);                                   \
    bf16x8 a1 = *(const bf16x8*)(&ArD[foA + 512]);                             \
    bf16x8 a2 = *(const bf16x8*)(&ArD[foA + 1024]);                            \
    bf16x8 a3 = *(const bf16x8*)(&ArD[foA + 1536]);                            \
    bf16x8 b0 = *(const bf16x8*)(&WrD[foB]);                                   \
    bf16x8 b1 = *(const bf16x8*)(&WrD[foB + 512]);                             \
    bf16x8 b2 = *(const bf16x8*)(&WrD[foB + 1024]);                            \
    bf16x8 b3 = *(const bf16x8*)(&WrD[foB + 1536]);                            \
    *(int4*)(&AwR[t * 8]) = aS;                                                \
    WPACK(0, WwR) WPACK(1, WwR) WPACK(2, WwR) WPACK(3, WwR)                    \
    { const int ii = (ST) + 2 < ns ? (ST) + 2 : ns - 1;                        \
      WLOADS(ii) }                                                             \
    acc00 = MFMA_BF16(a0, b0, acc00, 0, 0, 0);                                 \
    acc01 = MFMA_BF16(a0, b1, acc01, 0, 0, 0);                                 \
    acc02 = MFMA_BF16(a0, b2, acc02, 0, 0, 0);                                 \
    acc03 = MFMA_BF16(a0, b3, acc03, 0, 0, 0);                                 \
    acc10 = MFMA_BF16(a1, b0, acc10, 0, 0, 0);                                 \
    acc11 = MFMA_BF16(a1, b1, acc11, 0, 0, 0);                                 \
    acc12 = MFMA_BF16(a1, b2, acc12, 0, 0, 0);                                 \
    acc13 = MFMA_BF16(a1, b3, acc13, 0, 0, 0);                                 \
    acc20 = MFMA_BF16(a2, b0, acc20, 0, 0, 0);                                 \
    acc21 = MFMA_BF16(a2, b1, acc21, 0, 0, 0);                                 \
    acc22 = MFMA_BF16(a2, b2, acc22, 0, 0, 0);                                 \
    acc23 = MFMA_BF16(a2, b3, acc23, 0, 0, 0);                                 \
    acc30 = MFMA_BF16(a3, b0, acc30, 0, 0, 0);                                 \
    acc31 = MFMA_BF16(a3, b1, acc31, 0, 0, 0);                                 \
    acc32 = MFMA_BF16(a3, b2, acc32, 0, 0, 0);                                 \
    acc33 = MFMA_BF16(a3, b3, acc33, 0, 0, 0);                                 \
    asm volatile("s_waitcnt lgkmcnt(0)" ::: "memory");                         \
    __builtin_amdgcn_s_barrier();                                              \
    asm volatile("" ::: "memory");                                             \
  }

__global__ __launch_bounds__(256) void k_gemm(
    const u16* __restrict__ A0, const u16* __restrict__ A1, int lda0, int lda1,
    const float* __restrict__ W0, const float* __restrict__ W1, int Nw,
    int tot0, int tot1, int per0, int per1, int slabBase1,
    float* __restrict__ Cs)
{
  __shared__ u16 lA0[2048];     // A: 64 rows x 32 k bf16, 16B-chunk XOR swizzle
  __shared__ u16 lA1[2048];
  __shared__ u16 lW0[8192];     // W^T: [n=256][k=32] bf16, sw(n) XOR on k-chunks
  __shared__ u16 lW1[8192];

  const u16* A; int lda; const float* W; int tot, per, slab;
  if (blockIdx.z == 0) { A = A0; lda = lda0; W = W0; tot = tot0; per = per0; slab = blockIdx.y; }
  else                 { A = A1; lda = lda1; W = W1; tot = tot1; per = per1; slab = slabBase1 + blockIdx.y; }

  const int n0  = blockIdx.x << 8;                  // 256-col tiles
  const int sp0 = blockIdx.y * per;
  int ns = tot - sp0; if (ns > per) ns = per;
  if (ns <= 0) return;
  const int t  = threadIdx.x;
  const int l  = t & 63;
  const int wv = t >> 6;

  // A staging: thread t -> row t>>2, 16B chunk (t&3)^swA(row); LDS linear t*8
  const int rA  = t >> 2;
  const int cAg = (t & 3) ^ ((rA >> 1) & 3);
  const u16* gA = A + (size_t)rA * lda + cAg * 8 + (size_t)sp0 * 32;

  // W staging: wave wv owns k-rows 8wv..8wv+7; lane l covers 16B at col l*4
  const float* gW = W + (size_t)(sp0 * 32 + wv * 8) * Nw + n0 + l * 4;
  const size_t stepW = (size_t)32 * Nw;

  // fragment read offsets (elements)
  const int g4 = l >> 4;
  const int li = l & 15;
  const int foA = li * 32 + ((g4 ^ ((li >> 1) & 3)) << 3);               // + rt*512
  const int foB = wv * 2048 + li * 32 +
                  ((g4 ^ (((li >> 1) ^ (li >> 2)) & 3)) << 3);           // + ct*512

  f32x4 z4 = {0.f, 0.f, 0.f, 0.f};
  f32x4 acc00 = z4, acc01 = z4, acc02 = z4, acc03 = z4;
  f32x4 acc10 = z4, acc11 = z4, acc12 = z4, acc13 = z4;
  f32x4 acc20 = z4, acc21 = z4, acc22 = z4, acc23 = z4;
  f32x4 acc30 = z4, acc31 = z4, acc32 = z4, acc33 = z4;

  f32x4 ws0, ws1, ws2, ws3, ws4, ws5, ws6, ws7;
  int4 aS;

  // ---- prologue: tile0 -> regs -> buf0; issue tile1; barrier ----
  WLOADS(0)
  *(int4*)(&lA0[t * 8]) = aS;
  WPACK(0, lW0) WPACK(1, lW0) WPACK(2, lW0) WPACK(3, lW0)
  { const int i1 = 1 < ns ? 1 : 0;
    WLOADS(i1) }
  asm volatile("s_waitcnt lgkmcnt(0)" ::: "memory");
  __builtin_amdgcn_s_barrier();
  asm volatile("" ::: "memory");

  // ---- main loop: 2-unrolled for static buffer names ----
  int st = 0;
  for (; st + 2 <= ns; st += 2) {
    GEMM_STEP(st,     lA0, lW0, lA1, lW1)
    GEMM_STEP(st + 1, lA1, lW1, lA0, lW0)
  }
  if (st < ns) {
    GEMM_STEP(st, lA0, lW0, lA1, lW1)
  }

  // store: row = rt*16 + g4*4 + j, col = n0 + wv*64 + ct*16 + li
  float* base = Cs + (size_t)slab * NB * Nw + n0 + wv * 64 + li;
  #pragma unroll
  for (int j = 0; j < 4; ++j) {
    float* r0 = base + (size_t)(g4 * 4 + j) * Nw;
    r0[0]                    = acc00[j];
    r0[16]                   = acc01[j];
    r0[32]                   = acc02[j];
    r0[48]                   = acc03[j];
    float* r1 = r0 + 16 * Nw;
    r1[0]                    = acc10[j];
    r1[16]                   = acc11[j];
    r1[32]                   = acc12[j];
    r1[48]                   = acc13[j];
    float* r2 = r0 + 32 * Nw;
    r2[0]                    = acc20[j];
    r2[16]                   = acc21[j];
    r2[32]                   = acc22[j];
    r2[48]                   = acc23[j];
    float* r3 = r0 + 48 * Nw;
    r3[0]                    = acc30[j];
    r3[16]                   = acc31[j];
    r3[32]                   = acc32[j];
    r3[48]                   = acc33[j];
  }
}

// ---------- epilogues ----------
__global__ void k_ep12(const float* __restrict__ Cs,
                       const float* __restrict__ b1, const float* __restrict__ b2,
                       u16* __restrict__ A3) {
  int i = blockIdx.x * 256 + threadIdx.x;
  if (i >= NB * H3) return;
  float mix = b1[i & (H3 - 1)];
  float v   = b2[i & (H3 - 1)];
  #pragma unroll 4
  for (int s = 0; s < 16; ++s)  mix += Cs[(size_t)s * (NB * H3) + i];
  #pragma unroll 4
  for (int s = 16; s < 32; ++s) v   += Cs[(size_t)s * (NB * H3) + i];
  mix = mix > 0.f ? mix : 0.f;
  v   = v   > 0.f ? v   : 0.f;
  A3[i] = f2b(v + mix);
}

__global__ void k_ep(const float* __restrict__ Cs, int nslab, int slabElems,
                     const float* __restrict__ bias, u16* __restrict__ outb,
                     int colmask, int total) {
  int i = blockIdx.x * 256 + threadIdx.x;
  if (i >= total) return;
  float v = bias[i & colmask];
  #pragma unroll 4
  for (int s = 0; s < nslab; ++s) v += Cs[(size_t)s * slabElems + i];
  v = v > 0.f ? v : 0.f;
  outb[i] = f2b(v);
}

__global__ void k_ep5(const float* __restrict__ Cs, int nslab,
                      const float* __restrict__ bz, float* __restrict__ out) {
  int i = blockIdx.x * 256 + threadIdx.x;
  if (i >= NB * LATD) return;
  float v = bz[i & 511];
  #pragma unroll 4
  for (int s = 0; s < nslab; ++s) v += Cs[(size_t)s * (NB * LATD) + i];
  v = v > 0.f ? v : 0.f;
  out[i] = v;
  out[NB * LATD + i] = v;   // z_mean and z_logvar identical
}

extern "C" void kernel_launch(void* const* d_in, const int* in_sizes, int n_in,
                              void* d_out, int out_size, void* d_ws, size_t ws_size,
                              hipStream_t stream) {
  const int*   E    = (const int*)d_in[0];
  const float* X    = (const float*)d_in[1];
  const float* cls  = (const float*)d_in[2];
  const float* Wg1  = (const float*)d_in[3];
  const float* Wg2  = (const float*)d_in[4];
  const float* Wbox = (const float*)d_in[5];
  const float* bbox = (const float*)d_in[6];
  const float* Wlbl = (const float*)d_in[7];
  const float* blbl = (const float*)d_in[8];
  const float* Wd1  = (const float*)d_in[9];
  const float* bd1  = (const float*)d_in[10];
  const float* Wd2  = (const float*)d_in[11];
  const float* bd2  = (const float*)d_in[12];
  const float* Wd3  = (const float*)d_in[13];
  const float* bd3  = (const float*)d_in[14];
  const float* Wz   = (const float*)d_in[15];
  const float* bz   = (const float*)d_in[16];

  // workspace map (~45 MiB; ws ~1 GiB)
  char* ws = (char*)d_ws;
  int*   cnt  = (int*)  (ws + 0x000000);  // 256 KB (memset)
  int*   off  = (int*)  (ws + 0x040000);  // 256 KB
  int*   cur  = (int*)  (ws + 0x080000);  // 256 KB
  int*   csr  = (int*)  (ws + 0x0C0000);  // 1 MB
  float* S1   = (float*)(ws + 0x1C0000);  // 2 MB (fully overwritten)
  float* S2   = (float*)(ws + 0x3C0000);  // 2 MB (fully overwritten)
  float* Wc   = (float*)(ws + 0x5C0000);  // 512 B
  u16*   A3   = (u16*)  (ws + 0x5C1000);  // 512 KB
  u16*   A4   = (u16*)  (ws + 0x641000);  // 512 KB
  u16*   A5   = (u16*)  (ws + 0x6C1000);  // 512 KB
  u16*   Mbuf = (u16*)  (ws + 0x741000);  // 2 MB
  u16*   Abuf = (u16*)  (ws + 0x941000);  // ~2.02 MB
  float* Cslb = (float*)(ws + 0xB50000);  // 32 slabs x 1 MB

  hipMemsetAsync(cnt, 0, 0x40000, stream);
  k_hist   <<<NEDGE / 256, 256, 0, stream>>>(E, cnt, Wg1, Wg2, Wc);
  k_scan   <<<1, 1024, 0, stream>>>(cnt, off, cur);
  k_scatter<<<NEDGE / 256, 256, 0, stream>>>(E, cur, csr);
  k_gather <<<NTOT * 8 / 256, 256, 0, stream>>>(off, cnt, csr, X,  S1);
  k_gather <<<NTOT * 8 / 256, 256, 0, stream>>>(off, cnt, csr, S1, S2);
  k_nodes  <<<NTOT * 16 / 256, 256, 0, stream>>>(S2, Wc, X, Wbox, bbox, Wlbl, blbl,
                                                 cls, Abuf, Mbuf);

  // GEMM1+2 merged (z=0: Mbuf@Wd1 -> slabs 0..15; z=1: Abuf@Wd2 -> slabs 16..31)
  { dim3 g(16, 16, 2);
    k_gemm<<<g, 256, 0, stream>>>(Mbuf, Abuf, K1, K2, Wd1, Wd2, H3,
                                  512, 517, 32, 33, 16, Cslb); }
  k_ep12<<<NB * H3 / 256, 256, 0, stream>>>(Cslb, bd1, bd2, A3);

  // GEMM3: A4 = relu(A3 @ Wd3 + b3)
  { dim3 g(16, 16, 1);
    k_gemm<<<g, 256, 0, stream>>>(A3, A3, H3, H3, Wd3, Wd3, H3,
                                  128, 128, 8, 8, 0, Cslb); }
  k_ep<<<NB * H3 / 256, 256, 0, stream>>>(Cslb, 16, NB * H3, bd3, A4, H3 - 1, NB * H3);

  // GEMM4: A5 = relu(A4 @ Wd3 + b3)
  { dim3 g(16, 16, 1);
    k_gemm<<<g, 256, 0, stream>>>(A4, A4, H3, H3, Wd3, Wd3, H3,
                                  128, 128, 8, 8, 0, Cslb); }
  k_ep<<<NB * H3 / 256, 256, 0, stream>>>(Cslb, 16, NB * H3, bd3, A5, H3 - 1, NB * H3);

  // GEMM5: z = relu(A5 @ Wz + bz), written to both output halves
  { dim3 g(2, 32, 1);
    k_gemm<<<g, 256, 0, stream>>>(A5, A5, H3, H3, Wz, Wz, LATD,
                                  128, 128, 4, 4, 0, Cslb); }
  k_ep5<<<NB * LATD / 256, 256, 0, stream>>>(Cslb, 32, bz, (float*)d_out);
}